// Round 3
// baseline (963.109 us; speedup 1.0000x reference)
//
#include <hip/hip_runtime.h>
#include <stdint.h>

// ---------------- problem constants ----------------
#define K_H    8
#define K_D    64
#define K_G    64
#define K_DIM  256
#define K_INNER 512
#define K_B    4
#define K_N    32768

// ---------------- LDS layout ----------------
#define XS          264                   // x tile row stride (bf16 elems), 528B, 16B aligned
#define XLDS_BYTES  (64 * XS * 2)         // 33792
#define BUFA_STR    72                    // 144B rows, 16B aligned
#define BUFA_BYTES  (64 * BUFA_STR * 2)   // 9216
#define BUF2_STR    40                    // 80B rows, 16B aligned
#define BUF2_BYTES  (64 * BUF2_STR * 2)   // 5120
#define P1_WAVE_BYTES (BUFA_BYTES + BUF2_BYTES)         // 14336
#define P1_LDS      (XLDS_BYTES + 8 * P1_WAVE_BYTES)    // 148480  (<=160K)
#define OX_STR      520                   // 1040B rows, 16B aligned
#define OX_BYTES    (64 * OX_STR * 2)     // 66560
#define P3_LDS      (XLDS_BYTES + 8 * BUF2_BYTES + OX_BYTES)  // 141312
#define P2_LDS      (5 * 64 * 65 * 4 + 2 * 64 * 4)      // 83712

// ---------------- workspace layout (bytes) — identical to verified baseline ----------------
#define WFX_OFF   0
#define WX_OFF    (512 * 256 * 2)
#define WOUT_OFF  (WX_OFF + 512 * 256 * 2)
#define WSL_OFF   (WOUT_OFF + 256 * 512 * 2)
#define STN_OFF   (WSL_OFF + 64 * 64 * 2)
#define SNORM_OFF (STN_OFF + 4 * 8 * 64 * 64 * 4)
#define OST_OFF   (SNORM_OFF + 4 * 8 * 64 * 4)
// total = OST_OFF + 4*8*64*64*2 = ~1.6 MB (same as baseline)

// partial accumulators live in d_out (128 MiB; pass3 fully overwrites it later):
//   part_st: d_out floats [0, 256*8*4096)          = 32 MiB
//   part_sn: d_out floats [8388608, 8388608+131072) = 512 KiB
#define PART_ST_FLOATS (256 * 8 * 4096)   // 8388608

typedef __attribute__((ext_vector_type(8))) short short8;  // 8 x bf16 (4 VGPRs)
typedef __attribute__((ext_vector_type(4))) float f4;      // MFMA C/D frag
typedef __attribute__((ext_vector_type(4))) unsigned short us4;

static __device__ __forceinline__ f4 MFMA(short8 a, short8 b, f4 c) {
  return __builtin_amdgcn_mfma_f32_16x16x32_bf16(a, b, c, 0, 0, 0);
}
static __device__ __forceinline__ unsigned short f2bf(float f) {
  union { float f; unsigned u; } v; v.f = f;
  unsigned r = v.u + 0x7FFFu + ((v.u >> 16) & 1u);  // RNE
  return (unsigned short)(r >> 16);
}
static __device__ __forceinline__ us4 pack4(f4 v) {
  us4 p; p[0] = f2bf(v[0]); p[1] = f2bf(v[1]); p[2] = f2bf(v[2]); p[3] = f2bf(v[3]);
  return p;
}
// stage one 64x256 fp32 tile -> bf16 LDS [64][XS]
static __device__ __forceinline__ void stage_x(const float* __restrict__ xp,
                                               unsigned short* xlds, int tid) {
#pragma unroll
  for (int j = 0; j < 8; ++j) {
    int fi = j * 2048 + tid * 4;
    float4 v = *(const float4*)(xp + fi);
    int row = fi >> 8, col = fi & 255;
    us4 p; p[0] = f2bf(v.x); p[1] = f2bf(v.y); p[2] = f2bf(v.z); p[3] = f2bf(v.w);
    *(us4*)(xlds + row * XS + col) = p;
  }
}

// ---------------- prep: weights->bf16, zero accumulators ----------------
__global__ void prep_kernel(const float* __restrict__ Wfx, const float* __restrict__ Wx,
                            const float* __restrict__ Wsl, const float* __restrict__ Wout,
                            char* __restrict__ ws) {
  int idx = blockIdx.x * blockDim.x + threadIdx.x;
  int stride = gridDim.x * blockDim.x;
  unsigned short* wfxb  = (unsigned short*)(ws + WFX_OFF);
  unsigned short* wxb   = (unsigned short*)(ws + WX_OFF);
  unsigned short* woutb = (unsigned short*)(ws + WOUT_OFF);
  unsigned short* wslb  = (unsigned short*)(ws + WSL_OFF);
  for (int i = idx; i < 512 * 256; i += stride) wfxb[i] = f2bf(Wfx[i]);
  for (int i = idx; i < 512 * 256; i += stride) wxb[i]  = f2bf(Wx[i]);
  for (int i = idx; i < 256 * 512; i += stride) woutb[i] = f2bf(Wout[i]);
  for (int i = idx; i < 64 * 64; i += stride)   wslb[i] = f2bf(Wsl[i]);
  float* z = (float*)(ws + STN_OFF);
  for (int i = idx; i < 4 * 8 * 64 * 64 + 4 * 8 * 64; i += stride) z[i] = 0.0f;
}

// ---------------- pass1: proj + softmax + pool (persistent, wave = head) ----------------
// Accumulator flush: plain coalesced stores to a per-block private slice of d_out
// (scratch), replacing ~8.4M device-scope atomicAdd RMWs (~800 MB coherence traffic)
// with ~32 MB of streaming writes. reduce_kernel sums the slices afterwards.
__launch_bounds__(512, 2)
__global__ void pass1_kernel(const float* __restrict__ x,
                             const unsigned short* __restrict__ wfx,
                             const unsigned short* __restrict__ wx,
                             const unsigned short* __restrict__ wsl,
                             const float* __restrict__ bfx,
                             const float* __restrict__ bx,
                             const float* __restrict__ bsl,
                             const float* __restrict__ temp,
                             float* __restrict__ part_st,
                             float* __restrict__ part_sn) {
  extern __shared__ char lds[];
  const int tid = threadIdx.x;
  const int lane = tid & 63;
  const int h = tid >> 6;          // wave id == head
  const int l15 = lane & 15;
  const int q = lane >> 4;
  const int b = blockIdx.x >> 6;   // 64 blocks per batch
  const int blb = blockIdx.x & 63;

  unsigned short* xlds = (unsigned short*)lds;
  unsigned short* bufA = (unsigned short*)(lds + XLDS_BYTES + h * P1_WAVE_BYTES);
  unsigned short* buf2 = bufA + BUFA_BYTES / 2;

  const float inv_t = 1.0f / temp[h];
  float bfx_v[4];
#pragma unroll
  for (int ci = 0; ci < 4; ++ci) bfx_v[ci] = bfx[h * 64 + 16 * ci + l15];
  f4 bx_v[4];
#pragma unroll
  for (int mi = 0; mi < 4; ++mi)
#pragma unroll
    for (int r = 0; r < 4; ++r) bx_v[mi][r] = bx[h * 64 + 16 * mi + 4 * q + r];
  f4 bot[4];
#pragma unroll
  for (int gi = 0; gi < 4; ++gi)
#pragma unroll
    for (int r = 0; r < 4; ++r) bot[gi][r] = bsl[16 * gi + 4 * q + r] * inv_t;

  const f4 fz = {0.f, 0.f, 0.f, 0.f};
  f4 stacc[4][4];   // st[g][c] accumulator, persistent over the 8 tiles
  f4 snacc[4];      // snorm partial per lane
#pragma unroll
  for (int i = 0; i < 4; ++i) {
    snacc[i] = fz;
#pragma unroll
    for (int j = 0; j < 4; ++j) stacc[i][j] = fz;
  }

  for (int t = 0; t < 8; ++t) {
    const int n0 = (blb * 8 + t) * 64;
    const float* xp = x + ((size_t)b * K_N + n0) * K_DIM;
    __syncthreads();
    stage_x(xp, xlds, tid);
    __syncthreads();

    // ---- xm^T GEMM: D[d][n] = sum_k Wx[d][k] * x[n][k] ----
    f4 accX[4][4];
#pragma unroll
    for (int i = 0; i < 4; ++i)
#pragma unroll
      for (int j = 0; j < 4; ++j) accX[i][j] = fz;
#pragma unroll
    for (int ks = 0; ks < 8; ++ks) {
      short8 xb[4], wa[4];
#pragma unroll
      for (int ni = 0; ni < 4; ++ni)
        xb[ni] = *(const short8*)(xlds + (16 * ni + l15) * XS + 32 * ks + 8 * q);
#pragma unroll
      for (int mi = 0; mi < 4; ++mi)
        wa[mi] = *(const short8*)(wx + (size_t)(h * 64 + 16 * mi + l15) * K_DIM + 32 * ks + 8 * q);
#pragma unroll
      for (int mi = 0; mi < 4; ++mi)
#pragma unroll
        for (int ni = 0; ni < 4; ++ni)
          accX[mi][ni] = MFMA(wa[mi], xb[ni], accX[mi][ni]);
    }
    // flush xm[n][d] (fast quad writes: C rows d are contiguous)
#pragma unroll
    for (int mi = 0; mi < 4; ++mi)
#pragma unroll
      for (int ni = 0; ni < 4; ++ni) {
        f4 v = accX[mi][ni] + bx_v[mi];
        *(us4*)(bufA + (16 * ni + l15) * BUFA_STR + 16 * mi + 4 * q) = pack4(v);
      }

    // ---- logits^T GEMM: D[g][n] = sum_d Wsl[g][d] * xm[n][d] ----
    f4 accL[4][4];
#pragma unroll
    for (int i = 0; i < 4; ++i)
#pragma unroll
      for (int j = 0; j < 4; ++j) accL[i][j] = fz;
#pragma unroll
    for (int kh = 0; kh < 2; ++kh) {
      short8 wsa[4], xmb[4];
#pragma unroll
      for (int gi = 0; gi < 4; ++gi)
        wsa[gi] = *(const short8*)(wsl + (16 * gi + l15) * 64 + 32 * kh + 8 * q);
#pragma unroll
      for (int ni = 0; ni < 4; ++ni)
        xmb[ni] = *(const short8*)(bufA + (16 * ni + l15) * BUFA_STR + 32 * kh + 8 * q);
#pragma unroll
      for (int gi = 0; gi < 4; ++gi)
#pragma unroll
        for (int ni = 0; ni < 4; ++ni)
          accL[gi][ni] = MFMA(wsa[gi], xmb[ni], accL[gi][ni]);
    }
#pragma unroll
    for (int gi = 0; gi < 4; ++gi)
#pragma unroll
      for (int ni = 0; ni < 4; ++ni)
        accL[gi][ni] = accL[gi][ni] * inv_t + bot[gi];

    // ---- softmax over g (rows): in-lane over 16 regs + shuffle over quads ----
    unsigned swp[4][4][2];
#pragma unroll
    for (int ni = 0; ni < 4; ++ni) {
      float m = -3.0e38f;
#pragma unroll
      for (int gi = 0; gi < 4; ++gi)
#pragma unroll
        for (int r = 0; r < 4; ++r) m = fmaxf(m, accL[gi][ni][r]);
      m = fmaxf(m, __shfl_xor(m, 16));
      m = fmaxf(m, __shfl_xor(m, 32));
      float s = 0.f;
#pragma unroll
      for (int gi = 0; gi < 4; ++gi) {
        f4 e;
#pragma unroll
        for (int r = 0; r < 4; ++r) e[r] = __expf(accL[gi][ni][r] - m);
        accL[gi][ni] = e;
        s += e[0] + e[1] + e[2] + e[3];
      }
      s += __shfl_xor(s, 16);
      s += __shfl_xor(s, 32);
      const float rinv = 1.0f / s;
#pragma unroll
      for (int gi = 0; gi < 4; ++gi) {
        accL[gi][ni] *= rinv;
        snacc[gi] += accL[gi][ni];
        swp[gi][ni][0] = (unsigned)f2bf(accL[gi][ni][0]) | ((unsigned)f2bf(accL[gi][ni][1]) << 16);
        swp[gi][ni][1] = (unsigned)f2bf(accL[gi][ni][2]) | ((unsigned)f2bf(accL[gi][ni][3]) << 16);
      }
    }

    // ---- fx GEMM: D[n][c] = sum_k x[n][k] * Wfx[c][k] ----
    f4 accF[4][4];
#pragma unroll
    for (int i = 0; i < 4; ++i)
#pragma unroll
      for (int j = 0; j < 4; ++j) accF[i][j] = fz;
#pragma unroll
    for (int ks = 0; ks < 8; ++ks) {
      short8 xa[4], wb[4];
#pragma unroll
      for (int mi = 0; mi < 4; ++mi)
        xa[mi] = *(const short8*)(xlds + (16 * mi + l15) * XS + 32 * ks + 8 * q);
#pragma unroll
      for (int ci = 0; ci < 4; ++ci)
        wb[ci] = *(const short8*)(wfx + (size_t)(h * 64 + 16 * ci + l15) * K_DIM + 32 * ks + 8 * q);
#pragma unroll
      for (int mi = 0; mi < 4; ++mi)
#pragma unroll
        for (int ci = 0; ci < 4; ++ci)
          accF[mi][ci] = MFMA(xa[mi], wb[ci], accF[mi][ci]);
    }
    // flush fx^T[c][n] into bufA (overwrites xm; fast quad writes along n)
#pragma unroll
    for (int mi = 0; mi < 4; ++mi)
#pragma unroll
      for (int ci = 0; ci < 4; ++ci) {
        f4 v = accF[mi][ci] + bfx_v[ci];
        *(us4*)(bufA + (16 * ci + l15) * BUFA_STR + 16 * mi + 4 * q) = pack4(v);
      }

    // ---- pooling: st[g][c] += sum_n sw[n][g] * fx[n][c], K split in n-halves ----
#pragma unroll
    for (int kh = 0; kh < 2; ++kh) {
      // scalar-write sw^T[g][nloc] half (transpose via LDS)
#pragma unroll
      for (int gi = 0; gi < 4; ++gi)
#pragma unroll
        for (int nn = 0; nn < 2; ++nn) {
          const int ni = 2 * kh + nn;
#pragma unroll
          for (int r = 0; r < 4; ++r) {
            unsigned wv = swp[gi][ni][r >> 1];
            buf2[(16 * gi + 4 * q + r) * BUF2_STR + 16 * nn + l15] =
                (unsigned short)(wv >> (16 * (r & 1)));
          }
        }
      short8 aw[4], bw[4];
#pragma unroll
      for (int mt = 0; mt < 4; ++mt)
        aw[mt] = *(const short8*)(buf2 + (16 * mt + l15) * BUF2_STR + 8 * q);
#pragma unroll
      for (int ct = 0; ct < 4; ++ct)
        bw[ct] = *(const short8*)(bufA + (16 * ct + l15) * BUFA_STR + 32 * kh + 8 * q);
#pragma unroll
      for (int mt = 0; mt < 4; ++mt)
#pragma unroll
        for (int ct = 0; ct < 4; ++ct)
          stacc[mt][ct] = MFMA(aw[mt], bw[ct], stacc[mt][ct]);
    }
  }

  // ---- flush accumulators: plain stores to this block's private slice ----
  float* stp = part_st + (((size_t)blockIdx.x * 8 + h) << 12);
#pragma unroll
  for (int gi = 0; gi < 4; ++gi)
#pragma unroll
    for (int ci = 0; ci < 4; ++ci)
#pragma unroll
      for (int r = 0; r < 4; ++r)
        stp[(16 * gi + 4 * q + r) * 64 + 16 * ci + l15] = stacc[gi][ci][r];
  float* snp = part_sn + (((size_t)blockIdx.x * 8 + h) << 6);
#pragma unroll
  for (int gi = 0; gi < 4; ++gi)
#pragma unroll
    for (int r = 0; r < 4; ++r) {
      float vv = snacc[gi][r];
      vv += __shfl_xor(vv, 1);
      vv += __shfl_xor(vv, 2);
      vv += __shfl_xor(vv, 4);
      vv += __shfl_xor(vv, 8);
      if (l15 == 0) snp[16 * gi + 4 * q + r] = vv;
    }
}

// ---------------- reduce: sum 64 block-partials per (b,h) ----------------
// 131072 threads, one stnum output each; first 2048 also reduce snorm.
__global__ void reduce_kernel(const float* __restrict__ part_st,
                              const float* __restrict__ part_sn,
                              float* __restrict__ stnum,
                              float* __restrict__ snorm) {
  const int gid = blockIdx.x * blockDim.x + threadIdx.x;  // [0, 131072)
  const int i = gid & 4095;
  const int h = (gid >> 12) & 7;
  const int b = gid >> 15;
  // pass1 block index = b*64 + blb; its slice = (block*8 + h) * 4096
  const float* p = part_st + ((((size_t)b * 64) * 8 + h) << 12) + i;
  float s = 0.f;
#pragma unroll 8
  for (int blb = 0; blb < 64; ++blb) s += p[(size_t)blb * (8 * 4096)];
  stnum[(((size_t)b * 8 + h) << 12) + i] = s;
  if (gid < 2048) {
    const int g = gid & 63, h2 = (gid >> 6) & 7, b2 = gid >> 9;
    const float* ps = part_sn + ((((size_t)b2 * 64) * 8 + h2) << 6) + g;
    float s2 = 0.f;
#pragma unroll 8
    for (int blb = 0; blb < 64; ++blb) s2 += ps[(size_t)blb * (8 * 64)];
    snorm[(((size_t)b2 * 8 + h2) << 6) + g] = s2;
  }
}

// ---------------- pass2: tiny slice-token attention (fp32) ----------------
__global__ void pass2_kernel(const float* __restrict__ stnum, const float* __restrict__ snorm,
                             const float* __restrict__ Wq, const float* __restrict__ Wk,
                             const float* __restrict__ Wv, const float* __restrict__ attn_scale,
                             const float* __restrict__ res_scale,
                             unsigned short* __restrict__ ostT) {
  extern __shared__ char lds2[];
  float* st = (float*)lds2;        // [64][65]
  float* kv = st + 64 * 65;        // reused as attn later
  float* kk = kv + 64 * 65;
  float* vv = kk + 64 * 65;
  float* qq = vv + 64 * 65;
  float* nk = qq + 64 * 65;        // [64]
  float* nq = nk + 64;             // [64]
  const int b = blockIdx.x >> 3, h = blockIdx.x & 7;
  const int tid = threadIdx.x;

  float kvr[16], str[16];
#pragma unroll
  for (int j = 0; j < 16; ++j) kvr[j] = 0.f;
  for (int h2 = 0; h2 < 8; ++h2) {
    const float* np = stnum + ((size_t)b * 8 + h2) * 4096;
    const float* sp = snorm + ((size_t)b * 8 + h2) * 64;
#pragma unroll
    for (int j = 0; j < 16; ++j) {
      int idx = tid + 256 * j;
      int g = idx >> 6;
      float v = np[idx] / (sp[g] + 1e-5f);
      kvr[j] += v;
      if (h2 == h) str[j] = v;
    }
  }
#pragma unroll
  for (int j = 0; j < 16; ++j) {
    int idx = tid + 256 * j;
    int g = idx >> 6, d = idx & 63;
    st[g * 65 + d] = str[j];
    kv[g * 65 + d] = kvr[j] * 0.125f;
  }
  __syncthreads();
#pragma unroll 2
  for (int j = 0; j < 16; ++j) {
    int idx = tid + 256 * j;
    int g = idx >> 6, dp = idx & 63;
    float a1 = 0, a2 = 0, a3 = 0;
    for (int dd = 0; dd < 64; ++dd) {
      float kvv = kv[g * 65 + dd], stv = st[g * 65 + dd];
      a1 += kvv * Wk[dp * 64 + dd];
      a2 += kvv * Wv[dp * 64 + dd];
      a3 += stv * Wq[dp * 64 + dd];
    }
    kk[g * 65 + dp] = a1;
    vv[g * 65 + dp] = a2;
    qq[g * 65 + dp] = a3;
  }
  __syncthreads();
  if (tid < 128) {
    int g = tid & 63;
    const float* p = (tid >= 64) ? qq : kk;
    float s = 0;
    for (int d = 0; d < 64; ++d) { float v = p[g * 65 + d]; s += v * v; }
    float nrm = fmaxf(sqrtf(s), 1e-12f);
    ((tid >= 64) ? nq : nk)[g] = nrm;
  }
  __syncthreads();
  const float scale = attn_scale[h];
  float* at = kv;  // reuse
#pragma unroll 2
  for (int j = 0; j < 16; ++j) {
    int idx = tid + 256 * j;
    int g = idx >> 6, s2 = idx & 63;
    float a = 0;
    for (int d = 0; d < 64; ++d) a += qq[g * 65 + d] * kk[s2 * 65 + d];
    at[g * 65 + s2] = a * scale / (nq[g] * nk[s2]);
  }
  __syncthreads();
  if (tid < 64) {
    int g = tid;
    float m = -3.0e38f;
    for (int s2 = 0; s2 < 64; ++s2) m = fmaxf(m, at[g * 65 + s2]);
    float ssum = 0;
    for (int s2 = 0; s2 < 64; ++s2) {
      float e = __expf(at[g * 65 + s2] - m);
      at[g * 65 + s2] = e;
      ssum += e;
    }
    float r = 1.f / ssum;
    for (int s2 = 0; s2 < 64; ++s2) at[g * 65 + s2] *= r;
  }
  __syncthreads();
  const float rs = res_scale[0];
#pragma unroll 2
  for (int j = 0; j < 16; ++j) {
    int idx = tid + 256 * j;
    int g = idx >> 6, d = idx & 63;
    float o = 0;
    for (int s2 = 0; s2 < 64; ++s2) o += at[g * 65 + s2] * vv[s2 * 65 + d];
    o += rs * st[g * 65 + d];
    ostT[(((size_t)b * 8 + h) * 64 + d) * 64 + g] = f2bf(o);  // transposed [d][g]
  }
}

// ---------------- pass3: recompute sw, scatter, final GEMM ----------------
__launch_bounds__(512, 2)
__global__ void pass3_kernel(const float* __restrict__ x,
                             const unsigned short* __restrict__ wx,
                             const unsigned short* __restrict__ wsl,
                             const unsigned short* __restrict__ wout,
                             const unsigned short* __restrict__ ostT,
                             const float* __restrict__ bx,
                             const float* __restrict__ bsl,
                             const float* __restrict__ temp,
                             const float* __restrict__ bout,
                             float* __restrict__ out) {
  extern __shared__ char lds[];
  const int tid = threadIdx.x;
  const int lane = tid & 63;
  const int h = tid >> 6;
  const int l15 = lane & 15;
  const int q = lane >> 4;
  const int b = blockIdx.x >> 9;          // 512 blocks per batch
  const int n0 = (blockIdx.x & 511) * 64;

  unsigned short* xlds = (unsigned short*)lds;
  unsigned short* buf = (unsigned short*)(lds + XLDS_BYTES + h * BUF2_BYTES);
  unsigned short* ox = (unsigned short*)(lds + XLDS_BYTES + 8 * BUF2_BYTES);

  const float inv_t = 1.0f / temp[h];
  f4 bx_v[4], bot[4];
#pragma unroll
  for (int mi = 0; mi < 4; ++mi)
#pragma unroll
    for (int r = 0; r < 4; ++r) bx_v[mi][r] = bx[h * 64 + 16 * mi + 4 * q + r];
#pragma unroll
  for (int gi = 0; gi < 4; ++gi)
#pragma unroll
    for (int r = 0; r < 4; ++r) bot[gi][r] = bsl[16 * gi + 4 * q + r] * inv_t;
  float bout_v[2];
#pragma unroll
  for (int nt = 0; nt < 2; ++nt) bout_v[nt] = bout[32 * h + 16 * nt + l15];

  const float* xp = x + ((size_t)b * K_N + n0) * K_DIM;
  stage_x(xp, xlds, tid);
  __syncthreads();

  const f4 fz = {0.f, 0.f, 0.f, 0.f};
  // ---- xm^T GEMM ----
  f4 accX[4][4];
#pragma unroll
  for (int i = 0; i < 4; ++i)
#pragma unroll
    for (int j = 0; j < 4; ++j) accX[i][j] = fz;
#pragma unroll
  for (int ks = 0; ks < 8; ++ks) {
    short8 xb[4], wa[4];
#pragma unroll
    for (int ni = 0; ni < 4; ++ni)
      xb[ni] = *(const short8*)(xlds + (16 * ni + l15) * XS + 32 * ks + 8 * q);
#pragma unroll
    for (int mi = 0; mi < 4; ++mi)
      wa[mi] = *(const short8*)(wx + (size_t)(h * 64 + 16 * mi + l15) * K_DIM + 32 * ks + 8 * q);
#pragma unroll
    for (int mi = 0; mi < 4; ++mi)
#pragma unroll
      for (int ni = 0; ni < 4; ++ni)
        accX[mi][ni] = MFMA(wa[mi], xb[ni], accX[mi][ni]);
  }
  // ---- half-flush xm + logits^T ----
  f4 accL[4][4];
#pragma unroll
  for (int i = 0; i < 4; ++i)
#pragma unroll
    for (int j = 0; j < 4; ++j) accL[i][j] = fz;
#pragma unroll
  for (int kh = 0; kh < 2; ++kh) {
#pragma unroll
    for (int mm = 0; mm < 2; ++mm) {
      const int mi = 2 * kh + mm;
#pragma unroll
      for (int ni = 0; ni < 4; ++ni) {
        f4 v = accX[mi][ni] + bx_v[mi];
        *(us4*)(buf + (16 * ni + l15) * BUF2_STR + 16 * mm + 4 * q) = pack4(v);
      }
    }
    short8 wsa[4], xmb[4];
#pragma unroll
    for (int gi = 0; gi < 4; ++gi)
      wsa[gi] = *(const short8*)(wsl + (16 * gi + l15) * 64 + 32 * kh + 8 * q);
#pragma unroll
    for (int ni = 0; ni < 4; ++ni)
      xmb[ni] = *(const short8*)(buf + (16 * ni + l15) * BUF2_STR + 8 * q);
#pragma unroll
    for (int gi = 0; gi < 4; ++gi)
#pragma unroll
      for (int ni = 0; ni < 4; ++ni)
        accL[gi][ni] = MFMA(wsa[gi], xmb[ni], accL[gi][ni]);
  }
#pragma unroll
  for (int gi = 0; gi < 4; ++gi)
#pragma unroll
    for (int ni = 0; ni < 4; ++ni)
      accL[gi][ni] = accL[gi][ni] * inv_t + bot[gi];
  // ---- softmax over g ----
#pragma unroll
  for (int ni = 0; ni < 4; ++ni) {
    float m = -3.0e38f;
#pragma unroll
    for (int gi = 0; gi < 4; ++gi)
#pragma unroll
      for (int r = 0; r < 4; ++r) m = fmaxf(m, accL[gi][ni][r]);
    m = fmaxf(m, __shfl_xor(m, 16));
    m = fmaxf(m, __shfl_xor(m, 32));
    float s = 0.f;
#pragma unroll
    for (int gi = 0; gi < 4; ++gi) {
      f4 e;
#pragma unroll
      for (int r = 0; r < 4; ++r) e[r] = __expf(accL[gi][ni][r] - m);
      accL[gi][ni] = e;
      s += e[0] + e[1] + e[2] + e[3];
    }
    s += __shfl_xor(s, 16);
    s += __shfl_xor(s, 32);
    const float rinv = 1.0f / s;
#pragma unroll
    for (int gi = 0; gi < 4; ++gi) accL[gi][ni] *= rinv;
  }
  // ---- scatter: D[d][n] = sum_g ost^T[d][g] * sw[n][g] ----
  f4 accO[4][4];
#pragma unroll
  for (int i = 0; i < 4; ++i)
#pragma unroll
    for (int j = 0; j < 4; ++j) accO[i][j] = fz;
  const unsigned short* op = ostT + ((size_t)b * 8 + h) * 4096;
#pragma unroll
  for (int kh = 0; kh < 2; ++kh) {
    // fast quad writes: sw[n][gloc] (C rows g contiguous)
#pragma unroll
    for (int gg = 0; gg < 2; ++gg) {
      const int gi = 2 * kh + gg;
#pragma unroll
      for (int ni = 0; ni < 4; ++ni)
        *(us4*)(buf + (16 * ni + l15) * BUF2_STR + 16 * gg + 4 * q) = pack4(accL[gi][ni]);
    }
    short8 ao[4], bo[4];
#pragma unroll
    for (int mt = 0; mt < 4; ++mt)
      ao[mt] = *(const short8*)(op + (16 * mt + l15) * 64 + 32 * kh + 8 * q);
#pragma unroll
    for (int ni = 0; ni < 4; ++ni)
      bo[ni] = *(const short8*)(buf + (16 * ni + l15) * BUF2_STR + 8 * q);
#pragma unroll
    for (int mt = 0; mt < 4; ++mt)
#pragma unroll
      for (int ni = 0; ni < 4; ++ni)
        accO[mt][ni] = MFMA(ao[mt], bo[ni], accO[mt][ni]);
  }
  // write out_x stripe into shared ox[n][c] (fast: C rows d contiguous)
#pragma unroll
  for (int mi = 0; mi < 4; ++mi)
#pragma unroll
    for (int ni = 0; ni < 4; ++ni)
      *(us4*)(ox + (16 * ni + l15) * OX_STR + h * 64 + 16 * mi + 4 * q) = pack4(accO[mi][ni]);
  __syncthreads();

  // ---- final GEMM: out[n][cout] = sum_c ox[n][c]*Wout[cout][c] + bout ----
  f4 accC[4][2];
#pragma unroll
  for (int i = 0; i < 4; ++i)
#pragma unroll
    for (int j = 0; j < 2; ++j) accC[i][j] = fz;
#pragma unroll
  for (int ks = 0; ks < 16; ++ks) {
    short8 ax[4], bw8[2];
#pragma unroll
    for (int mt = 0; mt < 4; ++mt)
      ax[mt] = *(const short8*)(ox + (16 * mt + l15) * OX_STR + 32 * ks + 8 * q);
#pragma unroll
    for (int nt = 0; nt < 2; ++nt)
      bw8[nt] = *(const short8*)(wout + (size_t)(32 * h + 16 * nt + l15) * 512 + 32 * ks + 8 * q);
#pragma unroll
    for (int mt = 0; mt < 4; ++mt)
#pragma unroll
      for (int nt = 0; nt < 2; ++nt)
        accC[mt][nt] = MFMA(ax[mt], bw8[nt], accC[mt][nt]);
  }
  float* op2 = out + ((size_t)b * K_N + n0) * K_DIM;
#pragma unroll
  for (int mt = 0; mt < 4; ++mt)
#pragma unroll
    for (int nt = 0; nt < 2; ++nt) {
      f4 v = accC[mt][nt] + bout_v[nt];
#pragma unroll
      for (int r = 0; r < 4; ++r)
        op2[(size_t)(16 * mt + 4 * q + r) * K_DIM + 32 * h + 16 * nt + l15] = v[r];
    }
}

// ---------------- host launch ----------------
extern "C" void kernel_launch(void* const* d_in, const int* in_sizes, int n_in,
                              void* d_out, int out_size, void* d_ws, size_t ws_size,
                              hipStream_t stream) {
  const float* x    = (const float*)d_in[0];
  const float* Wfx  = (const float*)d_in[1];
  const float* bfx  = (const float*)d_in[2];
  const float* Wx   = (const float*)d_in[3];
  const float* bx   = (const float*)d_in[4];
  const float* Wsl  = (const float*)d_in[5];
  const float* bsl  = (const float*)d_in[6];
  const float* temp = (const float*)d_in[7];
  const float* Wq   = (const float*)d_in[8];
  const float* Wk   = (const float*)d_in[9];
  const float* Wv   = (const float*)d_in[10];
  const float* rs   = (const float*)d_in[11];
  const float* asc  = (const float*)d_in[12];
  const float* Wout = (const float*)d_in[13];
  const float* bout = (const float*)d_in[14];
  float* out = (float*)d_out;
  char* ws = (char*)d_ws;

  unsigned short* wfxb  = (unsigned short*)(ws + WFX_OFF);
  unsigned short* wxb   = (unsigned short*)(ws + WX_OFF);
  unsigned short* woutb = (unsigned short*)(ws + WOUT_OFF);
  unsigned short* wslb  = (unsigned short*)(ws + WSL_OFF);
  float* stn = (float*)(ws + STN_OFF);
  float* snr = (float*)(ws + SNORM_OFF);
  unsigned short* ostb = (unsigned short*)(ws + OST_OFF);
  // partial accumulators live in d_out (128 MiB); pass3 overwrites all of d_out later.
  float* pst = out;                    // 8388608 floats = 32 MiB
  float* psn = out + PART_ST_FLOATS;   // 131072 floats  = 512 KiB

  // allow >64KB dynamic LDS (ignore errors; harmless under graph capture)
  (void)hipFuncSetAttribute((const void*)pass1_kernel,
                            hipFuncAttributeMaxDynamicSharedMemorySize, P1_LDS);
  (void)hipFuncSetAttribute((const void*)pass2_kernel,
                            hipFuncAttributeMaxDynamicSharedMemorySize, P2_LDS);
  (void)hipFuncSetAttribute((const void*)pass3_kernel,
                            hipFuncAttributeMaxDynamicSharedMemorySize, P3_LDS);

  prep_kernel<<<256, 256, 0, stream>>>(Wfx, Wx, Wsl, Wout, ws);
  pass1_kernel<<<256, 512, P1_LDS, stream>>>(x, wfxb, wxb, wslb, bfx, bx, bsl, temp,
                                             pst, psn);
  reduce_kernel<<<512, 256, 0, stream>>>(pst, psn, stn, snr);
  pass2_kernel<<<32, 256, P2_LDS, stream>>>(stn, snr, Wq, Wk, Wv, asc, rs, ostb);
  pass3_kernel<<<2048, 512, P3_LDS, stream>>>(x, wxb, wslb, woutb, ostb, bx, bsl, temp, bout, out);
}

// Round 5
// 868.599 us; speedup vs baseline: 1.1088x; 1.1088x over previous
//
#include <hip/hip_runtime.h>
#include <stdint.h>

// ---------------- problem constants ----------------
#define K_H    8
#define K_D    64
#define K_G    64
#define K_DIM  256
#define K_INNER 512
#define K_B    4
#define K_N    32768

// ---------------- LDS layout ----------------
#define XS          264                   // x tile row stride (bf16 elems), 528B, 16B aligned
#define XLDS_BYTES  (64 * XS * 2)         // 33792
#define BUFA_STR    72                    // 144B rows, 16B aligned
#define BUFA_BYTES  (64 * BUFA_STR * 2)   // 9216
#define BUF2_STR    40                    // 80B rows, 16B aligned
#define BUF2_BYTES  (64 * BUF2_STR * 2)   // 5120
#define P1_WAVE_BYTES (BUFA_BYTES + BUF2_BYTES)         // 14336
#define P1_LDS      (XLDS_BYTES + 8 * P1_WAVE_BYTES)    // 148480  (<=160K)
#define OX_STR      520                   // 1040B rows, 16B aligned
#define OX_BYTES    (64 * OX_STR * 2)     // 66560
#define P3_LDS      (XLDS_BYTES + 8 * BUF2_BYTES + OX_BYTES)  // 141312
#define P2_LDS      (5 * 64 * 65 * 4 + 2 * 64 * 4)      // 83712

// ---------------- workspace layout (bytes) — identical to verified baseline ----------------
#define WFX_OFF   0
#define WX_OFF    (512 * 256 * 2)
#define WOUT_OFF  (WX_OFF + 512 * 256 * 2)
#define WSL_OFF   (WOUT_OFF + 256 * 512 * 2)
#define STN_OFF   (WSL_OFF + 64 * 64 * 2)
#define SNORM_OFF (STN_OFF + 4 * 8 * 64 * 64 * 4)
#define OST_OFF   (SNORM_OFF + 4 * 8 * 64 * 4)
// total = OST_OFF + 4*8*64*64*2 = ~1.6 MB (same as baseline)

// partial accumulators live in d_out (128 MiB; pass3 fully overwrites it later):
//   part_st: d_out floats [0, 256*8*4096)          = 32 MiB
//   part_sn: d_out floats [8388608, 8388608+131072) = 512 KiB
#define PART_ST_FLOATS (256 * 8 * 4096)   // 8388608

typedef __attribute__((ext_vector_type(8))) short short8;  // 8 x bf16 (4 VGPRs)
typedef __attribute__((ext_vector_type(4))) float f4;      // MFMA C/D frag; also nt-load vehicle
typedef __attribute__((ext_vector_type(4))) unsigned short us4;

static __device__ __forceinline__ f4 MFMA(short8 a, short8 b, f4 c) {
  return __builtin_amdgcn_mfma_f32_16x16x32_bf16(a, b, c, 0, 0, 0);
}
static __device__ __forceinline__ unsigned short f2bf(float f) {
  union { float f; unsigned u; } v; v.f = f;
  unsigned r = v.u + 0x7FFFu + ((v.u >> 16) & 1u);  // RNE
  return (unsigned short)(r >> 16);
}
static __device__ __forceinline__ us4 pack4(f4 v) {
  us4 p; p[0] = f2bf(v[0]); p[1] = f2bf(v[1]); p[2] = f2bf(v[2]); p[3] = f2bf(v[3]);
  return p;
}
// stage one 64x256 fp32 tile -> bf16 LDS [64][XS]
// NON-TEMPORAL x loads (via ext_vector f4 — HIP float4 is a class the builtin
// rejects): x is read exactly once per pass; nt keeps the streaming x traffic
// from evicting the L2-resident weight matrices (round-3 counters showed
// ~620 MB/dispatch of weight re-fetch caused by x pollution).
static __device__ __forceinline__ void stage_x(const float* __restrict__ xp,
                                               unsigned short* xlds, int tid) {
#pragma unroll
  for (int j = 0; j < 8; ++j) {
    int fi = j * 2048 + tid * 4;
    f4 v = __builtin_nontemporal_load((const f4*)(xp + fi));
    int row = fi >> 8, col = fi & 255;
    us4 p; p[0] = f2bf(v[0]); p[1] = f2bf(v[1]); p[2] = f2bf(v[2]); p[3] = f2bf(v[3]);
    *(us4*)(xlds + row * XS + col) = p;
  }
}

// ---------------- prep: weights->bf16, zero accumulators ----------------
__global__ void prep_kernel(const float* __restrict__ Wfx, const float* __restrict__ Wx,
                            const float* __restrict__ Wsl, const float* __restrict__ Wout,
                            char* __restrict__ ws) {
  int idx = blockIdx.x * blockDim.x + threadIdx.x;
  int stride = gridDim.x * blockDim.x;
  unsigned short* wfxb  = (unsigned short*)(ws + WFX_OFF);
  unsigned short* wxb   = (unsigned short*)(ws + WX_OFF);
  unsigned short* woutb = (unsigned short*)(ws + WOUT_OFF);
  unsigned short* wslb  = (unsigned short*)(ws + WSL_OFF);
  for (int i = idx; i < 512 * 256; i += stride) wfxb[i] = f2bf(Wfx[i]);
  for (int i = idx; i < 512 * 256; i += stride) wxb[i]  = f2bf(Wx[i]);
  for (int i = idx; i < 256 * 512; i += stride) woutb[i] = f2bf(Wout[i]);
  for (int i = idx; i < 64 * 64; i += stride)   wslb[i] = f2bf(Wsl[i]);
  float* z = (float*)(ws + STN_OFF);
  for (int i = idx; i < 4 * 8 * 64 * 64 + 4 * 8 * 64; i += stride) z[i] = 0.0f;
}

// ---------------- pass1: proj + softmax + pool (persistent, wave = head) ----------------
__launch_bounds__(512, 2)
__global__ void pass1_kernel(const float* __restrict__ x,
                             const unsigned short* __restrict__ wfx,
                             const unsigned short* __restrict__ wx,
                             const unsigned short* __restrict__ wsl,
                             const float* __restrict__ bfx,
                             const float* __restrict__ bx,
                             const float* __restrict__ bsl,
                             const float* __restrict__ temp,
                             float* __restrict__ part_st,
                             float* __restrict__ part_sn) {
  extern __shared__ char lds[];
  const int tid = threadIdx.x;
  const int lane = tid & 63;
  const int h = tid >> 6;          // wave id == head
  const int l15 = lane & 15;
  const int q = lane >> 4;
  const int b = blockIdx.x >> 6;   // 64 blocks per batch
  const int blb = blockIdx.x & 63;

  unsigned short* xlds = (unsigned short*)lds;
  unsigned short* bufA = (unsigned short*)(lds + XLDS_BYTES + h * P1_WAVE_BYTES);
  unsigned short* buf2 = bufA + BUFA_BYTES / 2;

  const float inv_t = 1.0f / temp[h];
  float bfx_v[4];
#pragma unroll
  for (int ci = 0; ci < 4; ++ci) bfx_v[ci] = bfx[h * 64 + 16 * ci + l15];
  f4 bx_v[4];
#pragma unroll
  for (int mi = 0; mi < 4; ++mi)
#pragma unroll
    for (int r = 0; r < 4; ++r) bx_v[mi][r] = bx[h * 64 + 16 * mi + 4 * q + r];
  f4 bot[4];
#pragma unroll
  for (int gi = 0; gi < 4; ++gi)
#pragma unroll
    for (int r = 0; r < 4; ++r) bot[gi][r] = bsl[16 * gi + 4 * q + r] * inv_t;

  const f4 fz = {0.f, 0.f, 0.f, 0.f};
  f4 stacc[4][4];   // st[g][c] accumulator, persistent over the 8 tiles
  f4 snacc[4];      // snorm partial per lane
#pragma unroll
  for (int i = 0; i < 4; ++i) {
    snacc[i] = fz;
#pragma unroll
    for (int j = 0; j < 4; ++j) stacc[i][j] = fz;
  }

  for (int t = 0; t < 8; ++t) {
    const int n0 = (blb * 8 + t) * 64;
    const float* xp = x + ((size_t)b * K_N + n0) * K_DIM;
    __syncthreads();
    stage_x(xp, xlds, tid);
    __syncthreads();

    // ---- xm^T GEMM: D[d][n] = sum_k Wx[d][k] * x[n][k] ----
    f4 accX[4][4];
#pragma unroll
    for (int i = 0; i < 4; ++i)
#pragma unroll
      for (int j = 0; j < 4; ++j) accX[i][j] = fz;
#pragma unroll
    for (int ks = 0; ks < 8; ++ks) {
      short8 xb[4], wa[4];
#pragma unroll
      for (int ni = 0; ni < 4; ++ni)
        xb[ni] = *(const short8*)(xlds + (16 * ni + l15) * XS + 32 * ks + 8 * q);
#pragma unroll
      for (int mi = 0; mi < 4; ++mi)
        wa[mi] = *(const short8*)(wx + (size_t)(h * 64 + 16 * mi + l15) * K_DIM + 32 * ks + 8 * q);
#pragma unroll
      for (int mi = 0; mi < 4; ++mi)
#pragma unroll
        for (int ni = 0; ni < 4; ++ni)
          accX[mi][ni] = MFMA(wa[mi], xb[ni], accX[mi][ni]);
    }
    // flush xm[n][d] (fast quad writes: C rows d are contiguous)
#pragma unroll
    for (int mi = 0; mi < 4; ++mi)
#pragma unroll
      for (int ni = 0; ni < 4; ++ni) {
        f4 v = accX[mi][ni] + bx_v[mi];
        *(us4*)(bufA + (16 * ni + l15) * BUFA_STR + 16 * mi + 4 * q) = pack4(v);
      }

    // ---- logits^T GEMM: D[g][n] = sum_d Wsl[g][d] * xm[n][d] ----
    f4 accL[4][4];
#pragma unroll
    for (int i = 0; i < 4; ++i)
#pragma unroll
      for (int j = 0; j < 4; ++j) accL[i][j] = fz;
#pragma unroll
    for (int kh = 0; kh < 2; ++kh) {
      short8 wsa[4], xmb[4];
#pragma unroll
      for (int gi = 0; gi < 4; ++gi)
        wsa[gi] = *(const short8*)(wsl + (16 * gi + l15) * 64 + 32 * kh + 8 * q);
#pragma unroll
      for (int ni = 0; ni < 4; ++ni)
        xmb[ni] = *(const short8*)(bufA + (16 * ni + l15) * BUFA_STR + 32 * kh + 8 * q);
#pragma unroll
      for (int gi = 0; gi < 4; ++gi)
#pragma unroll
        for (int ni = 0; ni < 4; ++ni)
          accL[gi][ni] = MFMA(wsa[gi], xmb[ni], accL[gi][ni]);
    }
#pragma unroll
    for (int gi = 0; gi < 4; ++gi)
#pragma unroll
      for (int ni = 0; ni < 4; ++ni)
        accL[gi][ni] = accL[gi][ni] * inv_t + bot[gi];

    // ---- softmax over g (rows): in-lane over 16 regs + shuffle over quads ----
    unsigned swp[4][4][2];
#pragma unroll
    for (int ni = 0; ni < 4; ++ni) {
      float m = -3.0e38f;
#pragma unroll
      for (int gi = 0; gi < 4; ++gi)
#pragma unroll
        for (int r = 0; r < 4; ++r) m = fmaxf(m, accL[gi][ni][r]);
      m = fmaxf(m, __shfl_xor(m, 16));
      m = fmaxf(m, __shfl_xor(m, 32));
      float s = 0.f;
#pragma unroll
      for (int gi = 0; gi < 4; ++gi) {
        f4 e;
#pragma unroll
        for (int r = 0; r < 4; ++r) e[r] = __expf(accL[gi][ni][r] - m);
        accL[gi][ni] = e;
        s += e[0] + e[1] + e[2] + e[3];
      }
      s += __shfl_xor(s, 16);
      s += __shfl_xor(s, 32);
      const float rinv = 1.0f / s;
#pragma unroll
      for (int gi = 0; gi < 4; ++gi) {
        accL[gi][ni] *= rinv;
        snacc[gi] += accL[gi][ni];
        swp[gi][ni][0] = (unsigned)f2bf(accL[gi][ni][0]) | ((unsigned)f2bf(accL[gi][ni][1]) << 16);
        swp[gi][ni][1] = (unsigned)f2bf(accL[gi][ni][2]) | ((unsigned)f2bf(accL[gi][ni][3]) << 16);
      }
    }

    // ---- fx GEMM: D[n][c] = sum_k x[n][k] * Wfx[c][k] ----
    f4 accF[4][4];
#pragma unroll
    for (int i = 0; i < 4; ++i)
#pragma unroll
      for (int j = 0; j < 4; ++j) accF[i][j] = fz;
#pragma unroll
    for (int ks = 0; ks < 8; ++ks) {
      short8 xa[4], wb[4];
#pragma unroll
      for (int mi = 0; mi < 4; ++mi)
        xa[mi] = *(const short8*)(xlds + (16 * mi + l15) * XS + 32 * ks + 8 * q);
#pragma unroll
      for (int ci = 0; ci < 4; ++ci)
        wb[ci] = *(const short8*)(wfx + (size_t)(h * 64 + 16 * ci + l15) * K_DIM + 32 * ks + 8 * q);
#pragma unroll
      for (int mi = 0; mi < 4; ++mi)
#pragma unroll
        for (int ci = 0; ci < 4; ++ci)
          accF[mi][ci] = MFMA(xa[mi], wb[ci], accF[mi][ci]);
    }
    // flush fx^T[c][n] into bufA (overwrites xm; fast quad writes along n)
#pragma unroll
    for (int mi = 0; mi < 4; ++mi)
#pragma unroll
      for (int ci = 0; ci < 4; ++ci) {
        f4 v = accF[mi][ci] + bfx_v[ci];
        *(us4*)(bufA + (16 * ci + l15) * BUFA_STR + 16 * mi + 4 * q) = pack4(v);
      }

    // ---- pooling: st[g][c] += sum_n sw[n][g] * fx[n][c], K split in n-halves ----
#pragma unroll
    for (int kh = 0; kh < 2; ++kh) {
      // scalar-write sw^T[g][nloc] half (transpose via LDS)
#pragma unroll
      for (int gi = 0; gi < 4; ++gi)
#pragma unroll
        for (int nn = 0; nn < 2; ++nn) {
          const int ni = 2 * kh + nn;
#pragma unroll
          for (int r = 0; r < 4; ++r) {
            unsigned wv = swp[gi][ni][r >> 1];
            buf2[(16 * gi + 4 * q + r) * BUF2_STR + 16 * nn + l15] =
                (unsigned short)(wv >> (16 * (r & 1)));
          }
        }
      short8 aw[4], bw[4];
#pragma unroll
      for (int mt = 0; mt < 4; ++mt)
        aw[mt] = *(const short8*)(buf2 + (16 * mt + l15) * BUF2_STR + 8 * q);
#pragma unroll
      for (int ct = 0; ct < 4; ++ct)
        bw[ct] = *(const short8*)(bufA + (16 * ct + l15) * BUFA_STR + 32 * kh + 8 * q);
#pragma unroll
      for (int mt = 0; mt < 4; ++mt)
#pragma unroll
        for (int ct = 0; ct < 4; ++ct)
          stacc[mt][ct] = MFMA(aw[mt], bw[ct], stacc[mt][ct]);
    }
  }

  // ---- flush accumulators: non-temporal stores to this block's private slice ----
  float* stp = part_st + (((size_t)blockIdx.x * 8 + h) << 12);
#pragma unroll
  for (int gi = 0; gi < 4; ++gi)
#pragma unroll
    for (int ci = 0; ci < 4; ++ci)
#pragma unroll
      for (int r = 0; r < 4; ++r)
        __builtin_nontemporal_store(stacc[gi][ci][r],
                                    stp + (16 * gi + 4 * q + r) * 64 + 16 * ci + l15);
  float* snp = part_sn + (((size_t)blockIdx.x * 8 + h) << 6);
#pragma unroll
  for (int gi = 0; gi < 4; ++gi)
#pragma unroll
    for (int r = 0; r < 4; ++r) {
      float vv = snacc[gi][r];
      vv += __shfl_xor(vv, 1);
      vv += __shfl_xor(vv, 2);
      vv += __shfl_xor(vv, 4);
      vv += __shfl_xor(vv, 8);
      if (l15 == 0) __builtin_nontemporal_store(vv, snp + 16 * gi + 4 * q + r);
    }
}

// ---------------- reduce: sum 64 block-partials per (b,h) ----------------
// 131072 threads, one stnum output each; first 2048 also reduce snorm.
__global__ void reduce_kernel(const float* __restrict__ part_st,
                              const float* __restrict__ part_sn,
                              float* __restrict__ stnum,
                              float* __restrict__ snorm) {
  const int gid = blockIdx.x * blockDim.x + threadIdx.x;  // [0, 131072)
  const int i = gid & 4095;
  const int h = (gid >> 12) & 7;
  const int b = gid >> 15;
  // pass1 block index = b*64 + blb; its slice = (block*8 + h) * 4096
  const float* p = part_st + ((((size_t)b * 64) * 8 + h) << 12) + i;
  float s = 0.f;
#pragma unroll 8
  for (int blb = 0; blb < 64; ++blb)
    s += __builtin_nontemporal_load(p + (size_t)blb * (8 * 4096));
  stnum[(((size_t)b * 8 + h) << 12) + i] = s;
  if (gid < 2048) {
    const int g = gid & 63, h2 = (gid >> 6) & 7, b2 = gid >> 9;
    const float* ps = part_sn + ((((size_t)b2 * 64) * 8 + h2) << 6) + g;
    float s2 = 0.f;
#pragma unroll 8
    for (int blb = 0; blb < 64; ++blb)
      s2 += __builtin_nontemporal_load(ps + (size_t)blb * (8 * 64));
    snorm[(((size_t)b2 * 8 + h2) << 6) + g] = s2;
  }
}

// ---------------- pass2: tiny slice-token attention (fp32) ----------------
__global__ void pass2_kernel(const float* __restrict__ stnum, const float* __restrict__ snorm,
                             const float* __restrict__ Wq, const float* __restrict__ Wk,
                             const float* __restrict__ Wv, const float* __restrict__ attn_scale,
                             const float* __restrict__ res_scale,
                             unsigned short* __restrict__ ostT) {
  extern __shared__ char lds2[];
  float* st = (float*)lds2;        // [64][65]
  float* kv = st + 64 * 65;        // reused as attn later
  float* kk = kv + 64 * 65;
  float* vv = kk + 64 * 65;
  float* qq = vv + 64 * 65;
  float* nk = qq + 64 * 65;        // [64]
  float* nq = nk + 64;             // [64]
  const int b = blockIdx.x >> 3, h = blockIdx.x & 7;
  const int tid = threadIdx.x;

  float kvr[16], str[16];
#pragma unroll
  for (int j = 0; j < 16; ++j) kvr[j] = 0.f;
  for (int h2 = 0; h2 < 8; ++h2) {
    const float* np = stnum + ((size_t)b * 8 + h2) * 4096;
    const float* sp = snorm + ((size_t)b * 8 + h2) * 64;
#pragma unroll
    for (int j = 0; j < 16; ++j) {
      int idx = tid + 256 * j;
      int g = idx >> 6;
      float v = np[idx] / (sp[g] + 1e-5f);
      kvr[j] += v;
      if (h2 == h) str[j] = v;
    }
  }
#pragma unroll
  for (int j = 0; j < 16; ++j) {
    int idx = tid + 256 * j;
    int g = idx >> 6, d = idx & 63;
    st[g * 65 + d] = str[j];
    kv[g * 65 + d] = kvr[j] * 0.125f;
  }
  __syncthreads();
#pragma unroll 2
  for (int j = 0; j < 16; ++j) {
    int idx = tid + 256 * j;
    int g = idx >> 6, dp = idx & 63;
    float a1 = 0, a2 = 0, a3 = 0;
    for (int dd = 0; dd < 64; ++dd) {
      float kvv = kv[g * 65 + dd], stv = st[g * 65 + dd];
      a1 += kvv * Wk[dp * 64 + dd];
      a2 += kvv * Wv[dp * 64 + dd];
      a3 += stv * Wq[dp * 64 + dd];
    }
    kk[g * 65 + dp] = a1;
    vv[g * 65 + dp] = a2;
    qq[g * 65 + dp] = a3;
  }
  __syncthreads();
  if (tid < 128) {
    int g = tid & 63;
    const float* p = (tid >= 64) ? qq : kk;
    float s = 0;
    for (int d = 0; d < 64; ++d) { float v = p[g * 65 + d]; s += v * v; }
    float nrm = fmaxf(sqrtf(s), 1e-12f);
    ((tid >= 64) ? nq : nk)[g] = nrm;
  }
  __syncthreads();
  const float scale = attn_scale[h];
  float* at = kv;  // reuse
#pragma unroll 2
  for (int j = 0; j < 16; ++j) {
    int idx = tid + 256 * j;
    int g = idx >> 6, s2 = idx & 63;
    float a = 0;
    for (int d = 0; d < 64; ++d) a += qq[g * 65 + d] * kk[s2 * 65 + d];
    at[g * 65 + s2] = a * scale / (nq[g] * nk[s2]);
  }
  __syncthreads();
  if (tid < 64) {
    int g = tid;
    float m = -3.0e38f;
    for (int s2 = 0; s2 < 64; ++s2) m = fmaxf(m, at[g * 65 + s2]);
    float ssum = 0;
    for (int s2 = 0; s2 < 64; ++s2) {
      float e = __expf(at[g * 65 + s2] - m);
      at[g * 65 + s2] = e;
      ssum += e;
    }
    float r = 1.f / ssum;
    for (int s2 = 0; s2 < 64; ++s2) at[g * 65 + s2] *= r;
  }
  __syncthreads();
  const float rs = res_scale[0];
#pragma unroll 2
  for (int j = 0; j < 16; ++j) {
    int idx = tid + 256 * j;
    int g = idx >> 6, d = idx & 63;
    float o = 0;
    for (int s2 = 0; s2 < 64; ++s2) o += at[g * 65 + s2] * vv[s2 * 65 + d];
    o += rs * st[g * 65 + d];
    ostT[(((size_t)b * 8 + h) * 64 + d) * 64 + g] = f2bf(o);  // transposed [d][g]
  }
}

// ---------------- pass3: recompute sw, scatter, final GEMM ----------------
__launch_bounds__(512, 2)
__global__ void pass3_kernel(const float* __restrict__ x,
                             const unsigned short* __restrict__ wx,
                             const unsigned short* __restrict__ wsl,
                             const unsigned short* __restrict__ wout,
                             const unsigned short* __restrict__ ostT,
                             const float* __restrict__ bx,
                             const float* __restrict__ bsl,
                             const float* __restrict__ temp,
                             const float* __restrict__ bout,
                             float* __restrict__ out) {
  extern __shared__ char lds[];
  const int tid = threadIdx.x;
  const int lane = tid & 63;
  const int h = tid >> 6;
  const int l15 = lane & 15;
  const int q = lane >> 4;
  const int b = blockIdx.x >> 9;          // 512 blocks per batch
  const int n0 = (blockIdx.x & 511) * 64;

  unsigned short* xlds = (unsigned short*)lds;
  unsigned short* buf = (unsigned short*)(lds + XLDS_BYTES + h * BUF2_BYTES);
  unsigned short* ox = (unsigned short*)(lds + XLDS_BYTES + 8 * BUF2_BYTES);

  const float inv_t = 1.0f / temp[h];
  f4 bx_v[4], bot[4];
#pragma unroll
  for (int mi = 0; mi < 4; ++mi)
#pragma unroll
    for (int r = 0; r < 4; ++r) bx_v[mi][r] = bx[h * 64 + 16 * mi + 4 * q + r];
#pragma unroll
  for (int gi = 0; gi < 4; ++gi)
#pragma unroll
    for (int r = 0; r < 4; ++r) bot[gi][r] = bsl[16 * gi + 4 * q + r] * inv_t;
  float bout_v[2];
#pragma unroll
  for (int nt = 0; nt < 2; ++nt) bout_v[nt] = bout[32 * h + 16 * nt + l15];

  const float* xp = x + ((size_t)b * K_N + n0) * K_DIM;
  stage_x(xp, xlds, tid);
  __syncthreads();

  const f4 fz = {0.f, 0.f, 0.f, 0.f};
  // ---- xm^T GEMM ----
  f4 accX[4][4];
#pragma unroll
  for (int i = 0; i < 4; ++i)
#pragma unroll
    for (int j = 0; j < 4; ++j) accX[i][j] = fz;
#pragma unroll
  for (int ks = 0; ks < 8; ++ks) {
    short8 xb[4], wa[4];
#pragma unroll
    for (int ni = 0; ni < 4; ++ni)
      xb[ni] = *(const short8*)(xlds + (16 * ni + l15) * XS + 32 * ks + 8 * q);
#pragma unroll
    for (int mi = 0; mi < 4; ++mi)
      wa[mi] = *(const short8*)(wx + (size_t)(h * 64 + 16 * mi + l15) * K_DIM + 32 * ks + 8 * q);
#pragma unroll
    for (int mi = 0; mi < 4; ++mi)
#pragma unroll
      for (int ni = 0; ni < 4; ++ni)
        accX[mi][ni] = MFMA(wa[mi], xb[ni], accX[mi][ni]);
  }
  // ---- half-flush xm + logits^T ----
  f4 accL[4][4];
#pragma unroll
  for (int i = 0; i < 4; ++i)
#pragma unroll
    for (int j = 0; j < 4; ++j) accL[i][j] = fz;
#pragma unroll
  for (int kh = 0; kh < 2; ++kh) {
#pragma unroll
    for (int mm = 0; mm < 2; ++mm) {
      const int mi = 2 * kh + mm;
#pragma unroll
      for (int ni = 0; ni < 4; ++ni) {
        f4 v = accX[mi][ni] + bx_v[mi];
        *(us4*)(buf + (16 * ni + l15) * BUF2_STR + 16 * mm + 4 * q) = pack4(v);
      }
    }
    short8 wsa[4], xmb[4];
#pragma unroll
    for (int gi = 0; gi < 4; ++gi)
      wsa[gi] = *(const short8*)(wsl + (16 * gi + l15) * 64 + 32 * kh + 8 * q);
#pragma unroll
    for (int ni = 0; ni < 4; ++ni)
      xmb[ni] = *(const short8*)(buf + (16 * ni + l15) * BUF2_STR + 8 * q);
#pragma unroll
    for (int gi = 0; gi < 4; ++gi)
#pragma unroll
      for (int ni = 0; ni < 4; ++ni)
        accL[gi][ni] = MFMA(wsa[gi], xmb[ni], accL[gi][ni]);
  }
#pragma unroll
  for (int gi = 0; gi < 4; ++gi)
#pragma unroll
    for (int ni = 0; ni < 4; ++ni)
      accL[gi][ni] = accL[gi][ni] * inv_t + bot[gi];
  // ---- softmax over g ----
#pragma unroll
  for (int ni = 0; ni < 4; ++ni) {
    float m = -3.0e38f;
#pragma unroll
    for (int gi = 0; gi < 4; ++gi)
#pragma unroll
      for (int r = 0; r < 4; ++r) m = fmaxf(m, accL[gi][ni][r]);
    m = fmaxf(m, __shfl_xor(m, 16));
    m = fmaxf(m, __shfl_xor(m, 32));
    float s = 0.f;
#pragma unroll
    for (int gi = 0; gi < 4; ++gi) {
      f4 e;
#pragma unroll
      for (int r = 0; r < 4; ++r) e[r] = __expf(accL[gi][ni][r] - m);
      accL[gi][ni] = e;
      s += e[0] + e[1] + e[2] + e[3];
    }
    s += __shfl_xor(s, 16);
    s += __shfl_xor(s, 32);
    const float rinv = 1.0f / s;
#pragma unroll
    for (int gi = 0; gi < 4; ++gi) accL[gi][ni] *= rinv;
  }
  // ---- scatter: D[d][n] = sum_g ost^T[d][g] * sw[n][g] ----
  f4 accO[4][4];
#pragma unroll
  for (int i = 0; i < 4; ++i)
#pragma unroll
    for (int j = 0; j < 4; ++j) accO[i][j] = fz;
  const unsigned short* op = ostT + ((size_t)b * 8 + h) * 4096;
#pragma unroll
  for (int kh = 0; kh < 2; ++kh) {
    // fast quad writes: sw[n][gloc] (C rows g contiguous)
#pragma unroll
    for (int gg = 0; gg < 2; ++gg) {
      const int gi = 2 * kh + gg;
#pragma unroll
      for (int ni = 0; ni < 4; ++ni)
        *(us4*)(buf + (16 * ni + l15) * BUF2_STR + 16 * gg + 4 * q) = pack4(accL[gi][ni]);
    }
    short8 ao[4], bo[4];
#pragma unroll
    for (int mt = 0; mt < 4; ++mt)
      ao[mt] = *(const short8*)(op + (16 * mt + l15) * 64 + 32 * kh + 8 * q);
#pragma unroll
    for (int ni = 0; ni < 4; ++ni)
      bo[ni] = *(const short8*)(buf + (16 * ni + l15) * BUF2_STR + 8 * q);
#pragma unroll
    for (int mt = 0; mt < 4; ++mt)
#pragma unroll
      for (int ni = 0; ni < 4; ++ni)
        accO[mt][ni] = MFMA(ao[mt], bo[ni], accO[mt][ni]);
  }
  // write out_x stripe into shared ox[n][c] (fast: C rows d contiguous)
#pragma unroll
  for (int mi = 0; mi < 4; ++mi)
#pragma unroll
    for (int ni = 0; ni < 4; ++ni)
      *(us4*)(ox + (16 * ni + l15) * OX_STR + h * 64 + 16 * mi + 4 * q) = pack4(accO[mi][ni]);
  __syncthreads();

  // ---- final GEMM: out[n][cout] = sum_c ox[n][c]*Wout[cout][c] + bout ----
  f4 accC[4][2];
#pragma unroll
  for (int i = 0; i < 4; ++i)
#pragma unroll
    for (int j = 0; j < 2; ++j) accC[i][j] = fz;
#pragma unroll
  for (int ks = 0; ks < 16; ++ks) {
    short8 ax[4], bw8[2];
#pragma unroll
    for (int mt = 0; mt < 4; ++mt)
      ax[mt] = *(const short8*)(ox + (16 * mt + l15) * OX_STR + 32 * ks + 8 * q);
#pragma unroll
    for (int nt = 0; nt < 2; ++nt)
      bw8[nt] = *(const short8*)(wout + (size_t)(32 * h + 16 * nt + l15) * 512 + 32 * ks + 8 * q);
#pragma unroll
    for (int mt = 0; mt < 4; ++mt)
#pragma unroll
      for (int nt = 0; nt < 2; ++nt)
        accC[mt][nt] = MFMA(ax[mt], bw8[nt], accC[mt][nt]);
  }
  float* op2 = out + ((size_t)b * K_N + n0) * K_DIM;
#pragma unroll
  for (int mt = 0; mt < 4; ++mt)
#pragma unroll
    for (int nt = 0; nt < 2; ++nt) {
      f4 v = accC[mt][nt] + bout_v[nt];
#pragma unroll
      for (int r = 0; r < 4; ++r)
        __builtin_nontemporal_store(
            v[r], op2 + (size_t)(16 * mt + 4 * q + r) * K_DIM + 32 * h + 16 * nt + l15);
    }
}

// ---------------- host launch ----------------
extern "C" void kernel_launch(void* const* d_in, const int* in_sizes, int n_in,
                              void* d_out, int out_size, void* d_ws, size_t ws_size,
                              hipStream_t stream) {
  const float* x    = (const float*)d_in[0];
  const float* Wfx  = (const float*)d_in[1];
  const float* bfx  = (const float*)d_in[2];
  const float* Wx   = (const float*)d_in[3];
  const float* bx   = (const float*)d_in[4];
  const float* Wsl  = (const float*)d_in[5];
  const float* bsl  = (const float*)d_in[6];
  const float* temp = (const float*)d_in[7];
  const float* Wq   = (const float*)d_in[8];
  const float* Wk   = (const float*)d_in[9];
  const float* Wv   = (const float*)d_in[10];
  const float* rs   = (const float*)d_in[11];
  const float* asc  = (const float*)d_in[12];
  const float* Wout = (const float*)d_in[13];
  const float* bout = (const float*)d_in[14];
  float* out = (float*)d_out;
  char* ws = (char*)d_ws;

  unsigned short* wfxb  = (unsigned short*)(ws + WFX_OFF);
  unsigned short* wxb   = (unsigned short*)(ws + WX_OFF);
  unsigned short* woutb = (unsigned short*)(ws + WOUT_OFF);
  unsigned short* wslb  = (unsigned short*)(ws + WSL_OFF);
  float* stn = (float*)(ws + STN_OFF);
  float* snr = (float*)(ws + SNORM_OFF);
  unsigned short* ostb = (unsigned short*)(ws + OST_OFF);
  // partial accumulators live in d_out (128 MiB); pass3 overwrites all of d_out later.
  float* pst = out;                    // 8388608 floats = 32 MiB
  float* psn = out + PART_ST_FLOATS;   // 131072 floats  = 512 KiB

  // allow >64KB dynamic LDS (ignore errors; harmless under graph capture)
  (void)hipFuncSetAttribute((const void*)pass1_kernel,
                            hipFuncAttributeMaxDynamicSharedMemorySize, P1_LDS);
  (void)hipFuncSetAttribute((const void*)pass2_kernel,
                            hipFuncAttributeMaxDynamicSharedMemorySize, P2_LDS);
  (void)hipFuncSetAttribute((const void*)pass3_kernel,
                            hipFuncAttributeMaxDynamicSharedMemorySize, P3_LDS);

  prep_kernel<<<256, 256, 0, stream>>>(Wfx, Wx, Wsl, Wout, ws);
  pass1_kernel<<<256, 512, P1_LDS, stream>>>(x, wfxb, wxb, wslb, bfx, bx, bsl, temp,
                                             pst, psn);
  reduce_kernel<<<512, 256, 0, stream>>>(pst, psn, stn, snr);
  pass2_kernel<<<32, 256, P2_LDS, stream>>>(stn, snr, Wq, Wk, Wv, asc, rs, ostb);
  pass3_kernel<<<2048, 512, P3_LDS, stream>>>(x, wxb, wslb, woutb, ostb, bx, bsl, temp, bout, out);
}